// Round 1
// baseline (53.487 us; speedup 1.0000x reference)
//
#include <hip/hip_runtime.h>
#include <math.h>

#define HH 128
#define WW 128
#define NP (HH * WW)

// T = EPS - ln(GAUSS_TH) = 1e-7 + 0.35667494... (threshold in quad domain)
#define QTH   0.35667504f
#define QTHC  0.35680f   // slightly larger T for conservative culling

__global__ __launch_bounds__(256) void predhead_kernel(
    const float* __restrict__ vm,   // (B,3,H,W)
    const float* __restrict__ sm,   // (B,1,H,W)
    float* __restrict__ out,        // (B,1,H,W)
    int B)
{
    __shared__ float4 sP[256];   // a, b2, c, x
    __shared__ float  sY[256];   // y
    __shared__ int    s_cnt;

    const int t    = threadIdx.x;
    const int blk  = blockIdx.x;
    const int img  = blk >> 6;          // 64 tiles per image
    const int tile = blk & 63;
    const int ti0  = (tile >> 3) << 4;  // tile row origin
    const int tj0  = (tile & 7) << 4;   // tile col origin

    const int   prow = ti0 + (t >> 4);
    const int   pcol = tj0 + (t & 15);
    const float fpi  = (float)prow;
    const float fpj  = (float)pcol;
    const float lo_i = (float)ti0,  hi_i = (float)(ti0 + 15);
    const float lo_j = (float)tj0,  hi_j = (float)(tj0 + 15);

    const float* vb = vm + (size_t)img * 3 * NP;
    const float* sb = sm + (size_t)img * NP;

    float mq0 = 3.0e38f, mq1 = 3.0e38f;  // running min-quad (2 accumulators for ILP)

    for (int c0 = 0; c0 < NP; c0 += 256) {
        const int p = c0 + t;
        const float seg = sb[p];

        __syncthreads();              // previous chunk's survivors consumed
        if (t == 0) s_cnt = 0;
        __syncthreads();

        if (seg > 0.7f) {
            const float v0 = vb[p];
            const float v1 = vb[NP + p];
            const float v2 = vb[2 * NP + p];

            const float vh  = fmaxf(v0, 0.0f) + 1.0f;
            const float vw  = fmaxf(v1, 0.0f) + 1.0f;
            const float vh2 = vh * vh;
            const float vw2 = vw * vw;
            const float th  = 3.14f / (1.0f + expf(-v2));  // PI_APPROX * sigmoid
            float s, c;
            sincosf(th, &s, &c);
            const float s2 = s * s, c2 = c * c;
            const float ih = 0.5f / vh2, iw = 0.5f / vw2;
            const float a  = c2 * ih + s2 * iw;
            const float cc = s2 * ih + c2 * iw;
            const float b2 = 2.0f * s * c * (iw - ih);
            const float xf = (float)(p >> 7);        // row center
            const float yf = (float)(p & (WW - 1));  // col center

            // exact influence bbox of the {quad <= T} ellipse (+ fp margin)
            const float dim = sqrtf(2.0f * QTHC * (s2 * vw2 + c2 * vh2)) + 0.02f;
            const float djm = sqrtf(2.0f * QTHC * (c2 * vw2 + s2 * vh2)) + 0.02f;

            if (xf + dim >= lo_i && xf - dim <= hi_i &&
                yf + djm >= lo_j && yf - djm <= hi_j) {
                const int idx = atomicAdd(&s_cnt, 1);
                sP[idx] = make_float4(a, b2, cc, xf);
                sY[idx] = yf;
            }
        }
        __syncthreads();

        const int n = s_cnt;
        int k = 0;
        for (; k + 1 < n; k += 2) {
            const float4 P0 = sP[k];
            const float4 P1 = sP[k + 1];
            const float  y0 = sY[k];
            const float  y1 = sY[k + 1];
            const float di0 = fpi - P0.w, dj0 = fpj - y0;
            const float di1 = fpi - P1.w, dj1 = fpj - y1;
            const float q0 = fmaf(P0.x, di0 * di0,
                             fmaf(P0.y, di0 * dj0, P0.z * (dj0 * dj0)));
            const float q1 = fmaf(P1.x, di1 * di1,
                             fmaf(P1.y, di1 * dj1, P1.z * (dj1 * dj1)));
            mq0 = fminf(mq0, q0);
            mq1 = fminf(mq1, q1);
        }
        if (k < n) {
            const float4 P0 = sP[k];
            const float di0 = fpi - P0.w, dj0 = fpj - sY[k];
            const float q0 = fmaf(P0.x, di0 * di0,
                             fmaf(P0.y, di0 * dj0, P0.z * (dj0 * dj0)));
            mq0 = fminf(mq0, q0);
        }
    }

    const float mq = fminf(mq0, mq1);
    // out = gmax if gmax >= 0.7 else 0 ; gmax = exp(EPS - minq)
    const float g = (mq <= QTH) ? expf(1e-7f - mq) : 0.0f;
    out[(size_t)img * NP + prow * WW + pcol] = g;
}

extern "C" void kernel_launch(void* const* d_in, const int* in_sizes, int n_in,
                              void* d_out, int out_size, void* d_ws, size_t ws_size,
                              hipStream_t stream) {
    const float* vm = (const float*)d_in[0];
    const float* sm = (const float*)d_in[1];
    float* out = (float*)d_out;
    const int B = in_sizes[1] / NP;   // segmentation_map is (B,1,H,W)

    predhead_kernel<<<dim3(B * 64), dim3(256), 0, stream>>>(vm, sm, out, B);
}

// Round 2
// 19.695 us; speedup vs baseline: 2.7157x; 2.7157x over previous
//
#include <hip/hip_runtime.h>
#include <math.h>

#define HH 128
#define WW 128
#define NP (HH * WW)

// T = EPS - ln(GAUSS_TH) = 1e-7 + 0.35667494...
#define QTH   0.35667504f
#define QTHC  0.35680f   // slightly larger T for conservative culling
#define RB    8          // halo radius of the per-tile candidate window
#define CAPMX 2048       // max fallback entries

// ---------- fallback pre-pass: points whose reach exceeds the halo ----------
__global__ __launch_bounds__(256) void bigscan_kernel(
    const float* __restrict__ vm, const float* __restrict__ sm,
    float* __restrict__ ws, int cap, int total)
{
    const int p = blockIdx.x * 256 + threadIdx.x;
    if (p >= total) return;
    const int img = p >> 14;          // /NP
    const int pp  = p & (NP - 1);
    if (sm[(size_t)img * NP + pp] <= 0.7f) return;

    const float* vb = vm + (size_t)img * 3 * NP;
    const float v0 = vb[pp], v1 = vb[NP + pp], v2 = vb[2 * NP + pp];
    const float vh = fmaxf(v0, 0.f) + 1.f, vw = fmaxf(v1, 0.f) + 1.f;
    const float vh2 = vh * vh, vw2 = vw * vw;
    const float th = 3.14f / (1.f + expf(-v2));
    float s, c; sincosf(th, &s, &c);
    const float s2 = s * s, c2 = c * c;
    const float dim = sqrtf(2.f * QTHC * (s2 * vw2 + c2 * vh2)) + 0.02f;
    const float djm = sqrtf(2.f * QTHC * (c2 * vw2 + s2 * vh2)) + 0.02f;
    if (dim <= (float)RB - 0.5f && djm <= (float)RB - 0.5f) return;  // window covers it

    const float ih = 0.5f / vh2, iw = 0.5f / vw2;
    const float a  = c2 * ih + s2 * iw;
    const float cc = s2 * ih + c2 * iw;
    const float b2 = 2.f * s * c * (iw - ih);

    const int idx = atomicAdd((int*)ws, 1);
    if (idx < cap) {
        float* base = ws + 4;
        base[idx]           = a;
        base[cap + idx]     = b2;
        base[2 * cap + idx] = cc;
        base[3 * cap + idx] = (float)(pp >> 7);
        base[4 * cap + idx] = (float)(pp & (WW - 1));
        ((int*)base)[5 * cap + idx] = img;
    }
}

// ---------- main tile kernel: 16x16 tile, 32x32 candidate window ----------
__global__ __launch_bounds__(256) void predhead_kernel(
    const float* __restrict__ vm, const float* __restrict__ sm,
    float* __restrict__ out, const float* __restrict__ ws, int cap)
{
    __shared__ float4 sP[256];   // a, b2, c, x
    __shared__ float  sY[256];   // y
    __shared__ int    s_cnt;

    const int t    = threadIdx.x;
    const int blk  = blockIdx.x;
    const int img  = blk >> 6;
    const int tile = blk & 63;
    const int ti0  = (tile >> 3) << 4;
    const int tj0  = (tile & 7) << 4;

    const int   prow = ti0 + (t >> 4);
    const int   pcol = tj0 + (t & 15);
    const float fpi  = (float)prow;
    const float fpj  = (float)pcol;
    const float lo_i = (float)ti0,  hi_i = (float)(ti0 + 15);
    const float lo_j = (float)tj0,  hi_j = (float)(tj0 + 15);

    const float* vb = vm + (size_t)img * 3 * NP;
    const float* sb = sm + (size_t)img * NP;

    float mq0 = 3.0e38f, mq1 = 3.0e38f;

    #pragma unroll 1
    for (int chunk = 0; chunk < 4; ++chunk) {
        const int idx = (chunk << 8) + t;          // 0..1023 over 32x32 window
        const int r   = ti0 - RB + (idx >> 5);
        const int cI  = tj0 - RB + (idx & 31);
        const bool valid = ((unsigned)r < (unsigned)HH) && ((unsigned)cI < (unsigned)WW);
        const int p = r * WW + cI;
        const float seg = valid ? sb[p] : 0.0f;

        __syncthreads();              // previous chunk's survivors consumed
        if (t == 0) s_cnt = 0;
        __syncthreads();

        if (seg > 0.7f) {
            const float v0 = vb[p];
            const float v1 = vb[NP + p];
            const float v2 = vb[2 * NP + p];

            const float vh  = fmaxf(v0, 0.0f) + 1.0f;
            const float vw  = fmaxf(v1, 0.0f) + 1.0f;
            const float vh2 = vh * vh;
            const float vw2 = vw * vw;
            const float th  = 3.14f / (1.0f + expf(-v2));
            float s, c;
            sincosf(th, &s, &c);
            const float s2 = s * s, c2 = c * c;
            const float ih = 0.5f / vh2, iw = 0.5f / vw2;
            const float a  = c2 * ih + s2 * iw;
            const float cc = s2 * ih + c2 * iw;
            const float b2 = 2.0f * s * c * (iw - ih);
            const float xf = (float)r;
            const float yf = (float)cI;

            const float dim = sqrtf(2.0f * QTHC * (s2 * vw2 + c2 * vh2)) + 0.02f;
            const float djm = sqrtf(2.0f * QTHC * (c2 * vw2 + s2 * vh2)) + 0.02f;

            if (xf + dim >= lo_i && xf - dim <= hi_i &&
                yf + djm >= lo_j && yf - djm <= hi_j) {
                const int widx = atomicAdd(&s_cnt, 1);
                sP[widx] = make_float4(a, b2, cc, xf);
                sY[widx] = yf;
            }
        }
        __syncthreads();

        const int n = s_cnt;
        int k = 0;
        for (; k + 1 < n; k += 2) {
            const float4 P0 = sP[k];
            const float4 P1 = sP[k + 1];
            const float  y0 = sY[k];
            const float  y1 = sY[k + 1];
            const float di0 = fpi - P0.w, dj0 = fpj - y0;
            const float di1 = fpi - P1.w, dj1 = fpj - y1;
            const float q0 = fmaf(P0.x, di0 * di0,
                             fmaf(P0.y, di0 * dj0, P0.z * (dj0 * dj0)));
            const float q1 = fmaf(P1.x, di1 * di1,
                             fmaf(P1.y, di1 * dj1, P1.z * (dj1 * dj1)));
            mq0 = fminf(mq0, q0);
            mq1 = fminf(mq1, q1);
        }
        if (k < n) {
            const float4 P0 = sP[k];
            const float di0 = fpi - P0.w, dj0 = fpj - sY[k];
            const float q0 = fmaf(P0.x, di0 * di0,
                             fmaf(P0.y, di0 * dj0, P0.z * (dj0 * dj0)));
            mq0 = fminf(mq0, q0);
        }
    }

    // ---- exactness fallback: far-reaching points (expected: none) ----
    if (cap > 0) {
        const int nBig = min(((const int*)ws)[0], cap);
        const float* base = ws + 4;
        const int* ibase = (const int*)base;
        for (int k = 0; k < nBig; ++k) {
            if (ibase[5 * cap + k] != img) continue;
            const float a  = base[k];
            const float b2 = base[cap + k];
            const float cc = base[2 * cap + k];
            const float di = fpi - base[3 * cap + k];
            const float dj = fpj - base[4 * cap + k];
            const float q = fmaf(a, di * di, fmaf(b2, di * dj, cc * (dj * dj)));
            mq0 = fminf(mq0, q);
        }
    }

    const float mq = fminf(mq0, mq1);
    const float g = (mq <= QTH) ? expf(1e-7f - mq) : 0.0f;
    out[(size_t)img * NP + prow * WW + pcol] = g;
}

extern "C" void kernel_launch(void* const* d_in, const int* in_sizes, int n_in,
                              void* d_out, int out_size, void* d_ws, size_t ws_size,
                              hipStream_t stream) {
    const float* vm = (const float*)d_in[0];
    const float* sm = (const float*)d_in[1];
    float* out = (float*)d_out;
    float* ws  = (float*)d_ws;
    const int B = in_sizes[1] / NP;
    const int total = B * NP;

    int cap = 0;
    if (ws_size >= 16 + 24) {
        size_t c = (ws_size - 16) / 24;
        cap = (int)(c < CAPMX ? c : CAPMX);
    }

    if (cap > 0) {
        hipMemsetAsync(d_ws, 0, 16, stream);
        bigscan_kernel<<<dim3((total + 255) / 256), dim3(256), 0, stream>>>(
            vm, sm, ws, cap, total);
    }
    predhead_kernel<<<dim3(B * 64), dim3(256), 0, stream>>>(vm, sm, out, ws, cap);
}

// Round 3
// 13.854 us; speedup vs baseline: 3.8608x; 1.4216x over previous
//
#include <hip/hip_runtime.h>
#include <math.h>

#define HH 128
#define WW 128
#define NP (HH * WW)

// T = EPS - ln(GAUSS_TH) = 1e-7 + 0.35667494...
#define QTH   0.35667504f
#define QTHC  0.35680f   // slightly larger T for conservative culling
#define RB    8          // halo radius of candidate window
#define BIGV  7.84f      // max(v0,v1) above which reach may exceed halo (conservative)

__global__ __launch_bounds__(256) void predhead_fused(
    const float* __restrict__ vm,   // (B,3,H,W)
    const float* __restrict__ sm,   // (B,1,H,W)
    float* __restrict__ out,        // (B,1,H,W)
    int B)
{
    __shared__ float4 sP[1024];     // a, b2, c, packed x*128+y
    __shared__ int    s_cnt;

    const int t    = threadIdx.x;
    const int blk  = blockIdx.x;
    const int img  = blk >> 6;          // 64 tiles per image
    const int tile = blk & 63;
    const int ti0  = (tile >> 3) << 4;
    const int tj0  = (tile & 7) << 4;

    const int   prow = ti0 + (t >> 4);
    const int   pcol = tj0 + (t & 15);
    const float fpi  = (float)prow;
    const float fpj  = (float)pcol;
    const float lo_i = (float)ti0,  hi_i = (float)(ti0 + 15);
    const float lo_j = (float)tj0,  hi_j = (float)(tj0 + 15);

    const float* vb = vm + (size_t)img * 3 * NP;
    const float* sb = sm + (size_t)img * NP;

    if (t == 0) s_cnt = 0;

    // ---- issue window loads: whole 32x32 halo window as float4 (1/thread/plane)
    const int wr = ti0 - RB + (t >> 3);         // window row
    const int wc = tj0 - RB + ((t & 7) << 2);   // col-group start (mult of 4)
    // col groups are fully inside or fully outside [0,128); rows individually
    const bool wvalid = ((unsigned)wr < (unsigned)HH) && ((unsigned)wc < (unsigned)WW);
    const int p4 = (wr * WW + wc) >> 2;
    float4 seg4 = make_float4(0.f, 0.f, 0.f, 0.f);
    float4 v04 = seg4, v14 = seg4, v24 = seg4;
    if (wvalid) {
        seg4 = ((const float4*)sb)[p4];
        v04  = ((const float4*)vb)[p4];
        v14  = ((const float4*)(vb + NP))[p4];
        v24  = ((const float4*)(vb + 2 * NP))[p4];
    }

    // ---- far-reach screen over the whole image (v0,v1 planes only) ----
    // reach <= sqrt(2*QTHC)*max(vh,vw)+0.02 ; exceeds halo coverage only if
    // max(v0,v1) > BIGV. Superset screen => exact.
    bool big = false;
    {
        const float4* pl0 = (const float4*)vb;
        const float4* pl1 = (const float4*)(vb + NP);
        #pragma unroll 4
        for (int k = 0; k < 16; ++k) {
            const float4 a4 = pl0[t + (k << 8)];
            const float4 b4 = pl1[t + (k << 8)];
            const float m01 = fmaxf(fmaxf(a4.x, b4.x), fmaxf(a4.y, b4.y));
            const float m23 = fmaxf(fmaxf(a4.z, b4.z), fmaxf(a4.w, b4.w));
            big = big || (fmaxf(m01, m23) > BIGV);
        }
    }

    // ---- per-candidate params (4 candidates/thread, same row) ----
    float sg[4], a0[4], a1[4], a2[4];
    *(float4*)sg = seg4; *(float4*)a0 = v04; *(float4*)a1 = v14; *(float4*)a2 = v24;

    float4 cand[4];
    bool   cf[4];
    #pragma unroll
    for (int e = 0; e < 4; ++e) {
        const float vh  = fmaxf(a0[e], 0.f) + 1.f;
        const float vw  = fmaxf(a1[e], 0.f) + 1.f;
        const float vh2 = vh * vh, vw2 = vw * vw;
        const float th  = 3.14f / (1.f + expf(-a2[e]));
        float s, c; sincosf(th, &s, &c);
        const float s2 = s * s, c2 = c * c;
        const float ih = 0.5f / vh2, iw = 0.5f / vw2;
        const float a  = c2 * ih + s2 * iw;
        const float cc = s2 * ih + c2 * iw;
        const float b2 = 2.f * s * c * (iw - ih);
        const float xf = (float)wr;
        const float yf = (float)(wc + e);
        const float dim = sqrtf(2.f * QTHC * (s2 * vw2 + c2 * vh2)) + 0.02f;
        const float djm = sqrtf(2.f * QTHC * (c2 * vw2 + s2 * vh2)) + 0.02f;
        cf[e] = (sg[e] > 0.7f) &&
                (xf + dim >= lo_i) && (xf - dim <= hi_i) &&
                (yf + djm >= lo_j) && (yf - djm <= hi_j);
        cand[e] = make_float4(a, b2, cc, (float)(wr * WW + wc + e)); // packed x*128+y
    }

    __syncthreads();   // s_cnt init visible

    // ---- wave-aggregated compaction (4 ballots/wave, 1 atomic each) ----
    const int lane = t & 63;
    const unsigned long long lmlt = (lane == 63) ? 0x7fffffffffffffffull
                                                 : ((1ull << lane) - 1ull) | 0ull;
    #pragma unroll
    for (int e = 0; e < 4; ++e) {
        const unsigned long long mask = __ballot(cf[e]);
        if (mask) {
            const int leader = __ffsll((unsigned long long)mask) - 1;
            int base = 0;
            if (lane == leader) base = atomicAdd(&s_cnt, __popcll(mask));
            base = __shfl(base, leader);
            if (cf[e]) sP[base + __popcll(mask & ((1ull << lane) - 1ull))] = cand[e];
        }
    }

    const int anyBig = __syncthreads_or(big ? 1 : 0);
    const int n = s_cnt;

    // ---- eval survivors: min quad (2 accumulators) ----
    float mq0 = 3.0e38f, mq1 = 3.0e38f;
    int k = 0;
    for (; k + 1 < n; k += 2) {
        const float4 P0 = sP[k];
        const float4 P1 = sP[k + 1];
        const float x0 = floorf(P0.w * 0.0078125f);
        const float y0 = fmaf(x0, -128.f, P0.w);
        const float x1 = floorf(P1.w * 0.0078125f);
        const float y1 = fmaf(x1, -128.f, P1.w);
        const float di0 = fpi - x0, dj0 = fpj - y0;
        const float di1 = fpi - x1, dj1 = fpj - y1;
        const float q0 = fmaf(P0.x, di0 * di0,
                         fmaf(P0.y, di0 * dj0, P0.z * (dj0 * dj0)));
        const float q1 = fmaf(P1.x, di1 * di1,
                         fmaf(P1.y, di1 * dj1, P1.z * (dj1 * dj1)));
        mq0 = fminf(mq0, q0);
        mq1 = fminf(mq1, q1);
    }
    if (k < n) {
        const float4 P0 = sP[k];
        const float x0 = floorf(P0.w * 0.0078125f);
        const float y0 = fmaf(x0, -128.f, P0.w);
        const float di0 = fpi - x0, dj0 = fpj - y0;
        mq0 = fminf(mq0, fmaf(P0.x, di0 * di0,
                         fmaf(P0.y, di0 * dj0, P0.z * (dj0 * dj0))));
    }

    // ---- cold exact slow path: far-reaching points (expected: never) ----
    if (anyBig) {
        for (int c0 = 0; c0 < NP; c0 += 256) {
            __syncthreads();                 // sP free for reuse
            if (t == 0) s_cnt = 0;
            __syncthreads();
            const int p = c0 + t;
            const float seg = sb[p];
            const float v0 = vb[p], v1 = vb[NP + p];
            if (seg > 0.7f && fmaxf(v0, v1) > BIGV) {
                const float vh  = fmaxf(v0, 0.f) + 1.f;
                const float vw  = fmaxf(v1, 0.f) + 1.f;
                const float vh2 = vh * vh, vw2 = vw * vw;
                const float th  = 3.14f / (1.f + expf(-vb[2 * NP + p]));
                float s, c; sincosf(th, &s, &c);
                const float ih = 0.5f / vh2, iw = 0.5f / vw2;
                const float a  = c * c * ih + s * s * iw;
                const float cc = s * s * ih + c * c * iw;
                const float b2 = 2.f * s * c * (iw - ih);
                const int idx = atomicAdd(&s_cnt, 1);
                sP[idx] = make_float4(a, b2, cc, (float)p);
            }
            __syncthreads();
            const int nn = s_cnt;
            for (int kk = 0; kk < nn; ++kk) {
                const float4 P0 = sP[kk];
                const float x0 = floorf(P0.w * 0.0078125f);
                const float y0 = fmaf(x0, -128.f, P0.w);
                const float di = fpi - x0, dj = fpj - y0;
                mq0 = fminf(mq0, fmaf(P0.x, di * di,
                                 fmaf(P0.y, di * dj, P0.z * (dj * dj))));
            }
        }
    }

    const float mq = fminf(mq0, mq1);
    const float g = (mq <= QTH) ? expf(1e-7f - mq) : 0.0f;
    out[(size_t)img * NP + prow * WW + pcol] = g;
}

extern "C" void kernel_launch(void* const* d_in, const int* in_sizes, int n_in,
                              void* d_out, int out_size, void* d_ws, size_t ws_size,
                              hipStream_t stream) {
    const float* vm = (const float*)d_in[0];
    const float* sm = (const float*)d_in[1];
    float* out = (float*)d_out;
    const int B = in_sizes[1] / NP;

    predhead_fused<<<dim3(B * 64), dim3(256), 0, stream>>>(vm, sm, out, B);
}

// Round 4
// 10.945 us; speedup vs baseline: 4.8867x; 1.2657x over previous
//
#include <hip/hip_runtime.h>
#include <math.h>

#define HH 128
#define WW 128
#define NP (HH * WW)

// T = EPS - ln(GAUSS_TH) = 1e-7 + 0.35667494...
#define QTH   0.35667504f
#define QTHC  0.35680f   // slightly larger T for conservative culling
#define RB    8          // halo radius of candidate window
#define BIGV  7.84f      // max(v0,v1) above which reach may exceed halo (conservative)

__global__ __launch_bounds__(1024) void predhead_fused(
    const float* __restrict__ vm,   // (B,3,H,W)
    const float* __restrict__ sm,   // (B,1,H,W)
    float* __restrict__ out,        // (B,1,H,W)
    int B)
{
    __shared__ float4 sP[1024];     // a, b2, c, x
    __shared__ float  sY[1024];     // y
    __shared__ float  sRed[1024];   // 4:1 min-reduce
    __shared__ int    s_cnt;

    const int t    = threadIdx.x;   // 0..1023, 16 waves
    const int blk  = blockIdx.x;
    const int img  = blk >> 6;      // 64 tiles per image
    const int tile = blk & 63;
    const int ti0  = (tile >> 3) << 4;
    const int tj0  = (tile & 7) << 4;

    const int px  = t & 255;        // output pixel within tile
    const int sub = t >> 8;         // 0..3 eval slice
    const int prow = ti0 + (px >> 4);
    const int pcol = tj0 + (px & 15);
    const float fpi = (float)prow;
    const float fpj = (float)pcol;
    const float lo_i = (float)ti0,  hi_i = (float)(ti0 + 15);
    const float lo_j = (float)tj0,  hi_j = (float)(tj0 + 15);

    const float* vb = vm + (size_t)img * 3 * NP;
    const float* sb = sm + (size_t)img * NP;

    if (t == 0) s_cnt = 0;

    // ---- this thread's single window candidate (32x32 halo window) ----
    const int wr = ti0 - RB + (t >> 5);
    const int wc = tj0 - RB + (t & 31);
    const bool wv = ((unsigned)wr < (unsigned)HH) && ((unsigned)wc < (unsigned)WW);
    const int p = wr * WW + wc;
    float seg = 0.f, v0 = 0.f, v1 = 0.f, v2 = 0.f;
    if (wv) {
        seg = sb[p];
        v0  = vb[p];
        v1  = vb[NP + p];
        v2  = vb[2 * NP + p];
    }

    // ---- far-reach screen: whole image's v0/v1 planes, 8 float4/thread ----
    // reach <= sqrt(2*QTHC)*max(vh,vw)+0.02 ; can exceed halo only if
    // max(v0,v1) > BIGV. Superset screen => exact.
    const float4* pl0 = (const float4*)vb;
    const float4* pl1 = (const float4*)(vb + NP);
    float4 sc[8];
    #pragma unroll
    for (int k = 0; k < 4; ++k) {
        sc[k]     = pl0[t + (k << 10)];
        sc[4 + k] = pl1[t + (k << 10)];
    }
    bool big = false;
    #pragma unroll
    for (int k = 0; k < 8; ++k) {
        big = big || (fmaxf(fmaxf(sc[k].x, sc[k].y),
                            fmaxf(sc[k].z, sc[k].w)) > BIGV);
    }

    // ---- params for this candidate ----
    float4 cand;
    float  candy;
    bool   cf;
    {
        const float vh  = fmaxf(v0, 0.f) + 1.f;
        const float vw  = fmaxf(v1, 0.f) + 1.f;
        const float vh2 = vh * vh, vw2 = vw * vw;
        const float th  = 3.14f / (1.f + expf(-v2));
        float s, c; sincosf(th, &s, &c);
        const float s2 = s * s, c2 = c * c;
        const float ih = 0.5f / vh2, iw = 0.5f / vw2;
        const float a  = c2 * ih + s2 * iw;
        const float cc = s2 * ih + c2 * iw;
        const float b2 = 2.f * s * c * (iw - ih);
        const float xf = (float)wr;
        const float yf = (float)wc;
        const float dim = sqrtf(2.f * QTHC * (s2 * vw2 + c2 * vh2)) + 0.02f;
        const float djm = sqrtf(2.f * QTHC * (c2 * vw2 + s2 * vh2)) + 0.02f;
        cf = (seg > 0.7f) &&
             (xf + dim >= lo_i) && (xf - dim <= hi_i) &&
             (yf + djm >= lo_j) && (yf - djm <= hi_j);
        cand  = make_float4(a, b2, cc, xf);
        candy = yf;
    }

    __syncthreads();   // s_cnt init visible

    // ---- wave-aggregated compaction (1 ballot+atomic per wave) ----
    {
        const int lane = t & 63;
        const unsigned long long mask = __ballot(cf);
        if (mask) {
            const int leader = __ffsll((unsigned long long)mask) - 1;
            int base = 0;
            if (lane == leader) base = atomicAdd(&s_cnt, __popcll(mask));
            base = __shfl(base, leader);
            if (cf) {
                const int idx = base + __popcll(mask & ((1ull << lane) - 1ull));
                sP[idx] = cand;
                sY[idx] = candy;
            }
        }
    }

    const int anyBig = __syncthreads_or(big ? 1 : 0);
    const int n = s_cnt;

    // ---- eval: 4-way strided slice of survivors, 2 accumulators ----
    float m0 = 3.0e38f, m1 = 3.0e38f;
    int k = sub;
    for (; k + 4 < n; k += 8) {
        const float4 P0 = sP[k];
        const float  y0 = sY[k];
        const float4 P1 = sP[k + 4];
        const float  y1 = sY[k + 4];
        const float di0 = fpi - P0.w, dj0 = fpj - y0;
        const float di1 = fpi - P1.w, dj1 = fpj - y1;
        m0 = fminf(m0, fmaf(P0.x, di0 * di0,
                       fmaf(P0.y, di0 * dj0, P0.z * (dj0 * dj0))));
        m1 = fminf(m1, fmaf(P1.x, di1 * di1,
                       fmaf(P1.y, di1 * dj1, P1.z * (dj1 * dj1))));
    }
    if (k < n) {
        const float4 P0 = sP[k];
        const float  y0 = sY[k];
        const float di0 = fpi - P0.w, dj0 = fpj - y0;
        m0 = fminf(m0, fmaf(P0.x, di0 * di0,
                       fmaf(P0.y, di0 * dj0, P0.z * (dj0 * dj0))));
    }

    // ---- cold exact slow path: far-reaching points (expected: never) ----
    if (anyBig) {
        for (int c0 = 0; c0 < NP; c0 += 1024) {
            __syncthreads();                 // sP free for reuse
            if (t == 0) s_cnt = 0;
            __syncthreads();
            const int pp = c0 + t;
            const float sg2 = sb[pp];
            const float w0 = vb[pp], w1 = vb[NP + pp];
            if (sg2 > 0.7f && fmaxf(w0, w1) > BIGV) {
                const float vh  = fmaxf(w0, 0.f) + 1.f;
                const float vw  = fmaxf(w1, 0.f) + 1.f;
                const float vh2 = vh * vh, vw2 = vw * vw;
                const float th  = 3.14f / (1.f + expf(-vb[2 * NP + pp]));
                float s, c; sincosf(th, &s, &c);
                const float ih = 0.5f / vh2, iw = 0.5f / vw2;
                const int idx = atomicAdd(&s_cnt, 1);
                sP[idx] = make_float4(c * c * ih + s * s * iw,
                                      2.f * s * c * (iw - ih),
                                      s * s * ih + c * c * iw,
                                      (float)(pp >> 7));
                sY[idx] = (float)(pp & (WW - 1));
            }
            __syncthreads();
            const int nn = s_cnt;
            for (int kk = 0; kk < nn; ++kk) {
                const float4 P0 = sP[kk];
                const float di = fpi - P0.w, dj = fpj - sY[kk];
                m0 = fminf(m0, fmaf(P0.x, di * di,
                               fmaf(P0.y, di * dj, P0.z * (dj * dj))));
            }
        }
    }

    // ---- 4:1 min-reduce and write ----
    __syncthreads();                 // eval reads of sP done
    sRed[t] = fminf(m0, m1);
    __syncthreads();
    if (t < 256) {
        const float mq = fminf(fminf(sRed[px], sRed[256 + px]),
                               fminf(sRed[512 + px], sRed[768 + px]));
        const float g = (mq <= QTH) ? expf(1e-7f - mq) : 0.0f;
        out[(size_t)img * NP + prow * WW + pcol] = g;
    }
}

extern "C" void kernel_launch(void* const* d_in, const int* in_sizes, int n_in,
                              void* d_out, int out_size, void* d_ws, size_t ws_size,
                              hipStream_t stream) {
    const float* vm = (const float*)d_in[0];
    const float* sm = (const float*)d_in[1];
    float* out = (float*)d_out;
    const int B = in_sizes[1] / NP;

    predhead_fused<<<dim3(B * 64), dim3(1024), 0, stream>>>(vm, sm, out, B);
}

// Round 6
// 9.982 us; speedup vs baseline: 5.3582x; 1.0965x over previous
//
#include <hip/hip_runtime.h>
#include <math.h>

#define HH 128
#define WW 128
#define NP (HH * WW)

// T = EPS - ln(GAUSS_TH) = 1e-7 + 0.35667494...
#define QTH   0.35667504f
#define QTHC  0.35680f   // slightly larger T for conservative culling
#define RB    8          // halo radius of candidate window
#define BIGV  7.84f      // max(v0,v1) above which reach may exceed halo (conservative)
#define NCAND 768        // 24 rows x 32 cols window

__global__ __launch_bounds__(1024) void predhead_fused(
    const float* __restrict__ vm,   // (B,3,H,W)
    const float* __restrict__ sm,   // (B,1,H,W)
    float* __restrict__ out,        // (B,1,H,W)
    int B)
{
    __shared__ float4 sP[1024];     // a, b2, c, x
    __shared__ float  sY[1024];     // y
    __shared__ float  sRed[1024];   // 8:1 min-reduce
    __shared__ int    s_cnt;

    const int t    = threadIdx.x;   // 0..1023, 16 waves
    const int blk  = blockIdx.x;
    const int img  = blk >> 7;      // 128 tiles per image
    const int tile = blk & 127;
    // 8x16 tiles: 16 tile-rows (128/8) x 8 tile-cols (128/16)
    const int ti0  = (tile >> 3) << 3;   // 0,8,...,120
    const int tj0  = (tile & 7) << 4;    // 0,16,...,112

    const int px   = t & 127;       // output pixel within 8x16 tile
    const int sub  = t >> 7;        // 0..7 eval slice
    const int prow = ti0 + (px >> 4);
    const int pcol = tj0 + (px & 15);
    const float fpi = (float)prow;
    const float fpj = (float)pcol;
    const float lo_i = (float)ti0,  hi_i = (float)(ti0 + 7);
    const float lo_j = (float)tj0,  hi_j = (float)(tj0 + 15);

    const float* vb = vm + (size_t)img * 3 * NP;
    const float* sb = sm + (size_t)img * NP;

    if (t == 0) s_cnt = 0;

    // ---- this thread's single window candidate (24x32 halo window) ----
    const int wr = ti0 - RB + (t >> 5);   // valid for t < 768
    const int wc = tj0 - RB + (t & 31);
    const bool own = (t < NCAND);
    const bool wv = own && ((unsigned)wr < (unsigned)HH) && ((unsigned)wc < (unsigned)WW);
    const int p = wr * WW + wc;
    float seg = 0.f, v0 = 0.f, v1 = 0.f, v2 = 0.f;
    if (wv) {
        seg = sb[p];
        v0  = vb[p];
        v1  = vb[NP + p];
        v2  = vb[2 * NP + p];
    }

    // ---- far-reach screen: whole image's v0/v1 planes, 8 float4/thread ----
    // reach <= sqrt(2*QTHC)*max(vh,vw)+0.02 ; can exceed halo only if
    // max(v0,v1) > BIGV. Superset screen => exact.
    const float4* pl0 = (const float4*)vb;
    const float4* pl1 = (const float4*)(vb + NP);
    float4 sc[8];
    #pragma unroll
    for (int k = 0; k < 4; ++k) {
        sc[k]     = pl0[t + (k << 10)];
        sc[4 + k] = pl1[t + (k << 10)];
    }
    bool big = false;
    #pragma unroll
    for (int k = 0; k < 8; ++k) {
        big = big || (fmaxf(fmaxf(sc[k].x, sc[k].y),
                            fmaxf(sc[k].z, sc[k].w)) > BIGV);
    }

    // ---- params for this candidate ----
    float4 cand;
    float  candy;
    bool   cf = false;
    if (own) {
        const float vh  = fmaxf(v0, 0.f) + 1.f;
        const float vw  = fmaxf(v1, 0.f) + 1.f;
        const float vh2 = vh * vh, vw2 = vw * vw;
        const float th  = 3.14f / (1.f + expf(-v2));
        float s, c; sincosf(th, &s, &c);
        const float s2 = s * s, c2 = c * c;
        const float ih = 0.5f / vh2, iw = 0.5f / vw2;
        const float a  = c2 * ih + s2 * iw;
        const float cc = s2 * ih + c2 * iw;
        const float b2 = 2.f * s * c * (iw - ih);
        const float xf = (float)wr;
        const float yf = (float)wc;
        const float dim = sqrtf(2.f * QTHC * (s2 * vw2 + c2 * vh2)) + 0.02f;
        const float djm = sqrtf(2.f * QTHC * (c2 * vw2 + s2 * vh2)) + 0.02f;
        cf = (seg > 0.7f) &&
             (xf + dim >= lo_i) && (xf - dim <= hi_i) &&
             (yf + djm >= lo_j) && (yf - djm <= hi_j);
        cand  = make_float4(a, b2, cc, xf);
        candy = yf;
    }

    __syncthreads();   // s_cnt init visible

    // ---- wave-aggregated compaction (1 ballot+atomic per wave) ----
    {
        const int lane = t & 63;
        const unsigned long long mask = __ballot(cf);
        if (mask) {
            const int leader = __ffsll((unsigned long long)mask) - 1;
            int base = 0;
            if (lane == leader) base = atomicAdd(&s_cnt, __popcll(mask));
            base = __shfl(base, leader);
            if (cf) {
                const int idx = base + __popcll(mask & ((1ull << lane) - 1ull));
                sP[idx] = cand;
                sY[idx] = candy;
            }
        }
    }

    const int anyBig = __syncthreads_or(big ? 1 : 0);
    const int n = s_cnt;

    // ---- eval: 8-way strided slice of survivors, 2 accumulators ----
    float m0 = 3.0e38f, m1 = 3.0e38f;
    int k = sub;
    for (; k + 8 < n; k += 16) {
        const float4 P0 = sP[k];
        const float  y0 = sY[k];
        const float4 P1 = sP[k + 8];
        const float  y1 = sY[k + 8];
        const float di0 = fpi - P0.w, dj0 = fpj - y0;
        const float di1 = fpi - P1.w, dj1 = fpj - y1;
        m0 = fminf(m0, fmaf(P0.x, di0 * di0,
                       fmaf(P0.y, di0 * dj0, P0.z * (dj0 * dj0))));
        m1 = fminf(m1, fmaf(P1.x, di1 * di1,
                       fmaf(P1.y, di1 * dj1, P1.z * (dj1 * dj1))));
    }
    if (k < n) {
        const float4 P0 = sP[k];
        const float  y0 = sY[k];
        const float di0 = fpi - P0.w, dj0 = fpj - y0;
        m0 = fminf(m0, fmaf(P0.x, di0 * di0,
                       fmaf(P0.y, di0 * dj0, P0.z * (dj0 * dj0))));
    }

    // ---- cold exact slow path: far-reaching points (expected: never) ----
    if (anyBig) {
        for (int c0 = 0; c0 < NP; c0 += 1024) {
            __syncthreads();                 // sP free for reuse
            if (t == 0) s_cnt = 0;
            __syncthreads();
            const int pp = c0 + t;
            const float sg2 = sb[pp];
            const float w0 = vb[pp], w1 = vb[NP + pp];
            if (sg2 > 0.7f && fmaxf(w0, w1) > BIGV) {
                const float vh  = fmaxf(w0, 0.f) + 1.f;
                const float vw  = fmaxf(w1, 0.f) + 1.f;
                const float vh2 = vh * vh, vw2 = vw * vw;
                const float th  = 3.14f / (1.f + expf(-vb[2 * NP + pp]));
                float s, c; sincosf(th, &s, &c);
                const float ih = 0.5f / vh2, iw = 0.5f / vw2;
                const int idx = atomicAdd(&s_cnt, 1);
                sP[idx] = make_float4(c * c * ih + s * s * iw,
                                      2.f * s * c * (iw - ih),
                                      s * s * ih + c * c * iw,
                                      (float)(pp >> 7));
                sY[idx] = (float)(pp & (WW - 1));
            }
            __syncthreads();
            const int nn = s_cnt;
            for (int kk = 0; kk < nn; ++kk) {
                const float4 P0 = sP[kk];
                const float di = fpi - P0.w, dj = fpj - sY[kk];
                m0 = fminf(m0, fmaf(P0.x, di * di,
                               fmaf(P0.y, di * dj, P0.z * (dj * dj))));
            }
        }
    }

    // ---- 8:1 min-reduce and write ----
    __syncthreads();                 // eval reads of sP done
    sRed[t] = fminf(m0, m1);
    __syncthreads();
    if (t < 128) {
        float mq = sRed[px];
        #pragma unroll
        for (int s8 = 1; s8 < 8; ++s8)
            mq = fminf(mq, sRed[s8 * 128 + px]);
        const float g = (mq <= QTH) ? expf(1e-7f - mq) : 0.0f;
        out[(size_t)img * NP + prow * WW + pcol] = g;
    }
}

extern "C" void kernel_launch(void* const* d_in, const int* in_sizes, int n_in,
                              void* d_out, int out_size, void* d_ws, size_t ws_size,
                              hipStream_t stream) {
    const float* vm = (const float*)d_in[0];
    const float* sm = (const float*)d_in[1];
    float* out = (float*)d_out;
    const int B = in_sizes[1] / NP;

    predhead_fused<<<dim3(B * 128), dim3(1024), 0, stream>>>(vm, sm, out, B);
}